// Round 22
// baseline (162.310 us; speedup 1.0000x reference)
//
#include <hip/hip_runtime.h>

namespace {

typedef unsigned short ushort_t;
typedef unsigned char u8;
typedef int i32x4 __attribute__((ext_vector_type(4)));
typedef float f32x4 __attribute__((ext_vector_type(4)));

constexpr int B_ = 2, C_ = 64, H_ = 192, W_ = 192;
constexpr int C4 = 256;
constexpr int NPIX = H_ * W_;                       // 36864
constexpr size_t NT = (size_t)B_ * C4 * NPIX;       // 18,874,368
constexpr int PB = NPIX / 32;                       // 1152 32-pixel blocks per batch
constexpr float EPSV = 1e-20f;
constexpr float QS = 16383.f;
constexpr float INVQS2 = 1.f / (16383.f * 16383.f);

constexpr int TILEW = 32, TILEH = 16;
constexpr int TLX = TILEW + 2;   // 34
constexpr int TLY = TILEH + 2;   // 18

struct TT { static constexpr bool value = true; };
struct FT { static constexpr bool value = false; };

__device__ __forceinline__ void async_ld16(const u8* g, u8* l) {
    __builtin_amdgcn_global_load_lds(
        (const __attribute__((address_space(1))) unsigned int*)g,
        (__attribute__((address_space(3))) unsigned int*)l, 16, 0, 0);
}

// quantize v in [0,1] to 14-bit, pack limbs into byte k of hw/lw
__device__ __forceinline__ void q14(float v, unsigned& hw, unsigned& lw, int k) {
    float qf = fminf(fmaf(v, QS, 0.5f), 16383.f);
    unsigned q = (unsigned)qf;                 // trunc; v >= 0 guaranteed
    hw |= (q >> 7)   << (8 * k);
    lw |= (q & 127u) << (8 * k);
}

// ---------------- cw -> u8 limb pair (14-bit fixed point) + partial sums -----
__global__ __launch_bounds__(256) void k_prep(const float* __restrict__ cw,
                                              u8* __restrict__ cwAh,
                                              u8* __restrict__ cwAl,
                                              float* __restrict__ partial) {
    __shared__ float red[256];
    int tid = threadIdx.x;
    int i = blockIdx.x * 256 + tid;   // grid 256 -> 65536 = [o][c4] row-major
    float w = cw[i];
    int qa = (int)rintf(w * QS);
    qa = qa < 0 ? 0 : (qa > 16383 ? 16383 : qa);
    cwAh[i] = (u8)(qa >> 7);
    cwAl[i] = (u8)(qa & 127);
    red[tid] = w; __syncthreads();
    for (int s2 = 128; s2 > 0; s2 >>= 1) { if (tid < s2) red[tid] += red[tid + s2]; __syncthreads(); }
    if (tid == 0) partial[blockIdx.x] = red[0];
}

// ---------------- tiny final reduction: sw sum + cw partials ----------------
__global__ __launch_bounds__(256) void k_sums2(const float* __restrict__ sw,
                                               const float* __restrict__ partial,
                                               float* __restrict__ sums) {
    __shared__ float red[256];
    int tid = threadIdx.x;
    float a = 0.f;
    for (int i = tid; i < C4 * 9; i += 256) a += sw[i];
    red[tid] = a; __syncthreads();
    for (int s2 = 128; s2 > 0; s2 >>= 1) { if (tid < s2) red[tid] += red[tid + s2]; __syncthreads(); }
    if (tid == 0) sums[0] = red[0];
    __syncthreads();
    red[tid] = partial[tid]; __syncthreads();
    for (int s2 = 128; s2 > 0; s2 >>= 1) { if (tid < s2) red[tid] += red[tid + s2]; __syncthreads(); }
    if (tid == 0) sums[1] = red[0];
}

// ---------------- fused stage 1 + stage 2 (depthwise conv) -------------------
// R21 structure (32x16 tile, ONE barrier, float2 u/v, u8 limb outputs, XCD
// swizzle) + VALU cuts: flattened fill (2+1 calls) with interior fast-path
// (no bounds ops for 40/72 tiles); conv weights via wave-uniform global reads
// (SGPR s_load, no LDS staging); trunc-based quantization.
__global__ __launch_bounds__(256) void k_stage12(
    const float* __restrict__ d, const float* __restrict__ cd,
    const float* __restrict__ s, const float* __restrict__ cs,
    const float* __restrict__ w_s_from_d, const float* __restrict__ w_prop,
    const float* __restrict__ sw, const float* __restrict__ sums,
    u8* __restrict__ XP, u8* __restrict__ YP)
{
    __shared__ float2 uv_[4][TLY][TLX];   // 19,584 B (u=.x, v=.y)

    int tid = threadIdx.x;
    // XCD-bijective swizzle: 9216 = 8*1152 -> neighbor tiles share an XCD L2.
    int orig = blockIdx.x;
    int blk = (orig & 7) * 1152 + (orig >> 3);
    constexpr int TX = W_ / TILEW, TY = H_ / TILEH;   // 6 x 12
    int tx0 = blk % TX; blk /= TX;
    int ty0 = blk % TY; blk /= TY;
    int c = blk % C_;
    int b = blk / C_;
    int h0 = ty0 * TILEH, w0 = tx0 * TILEW;

    const float* dbc  = d  + (size_t)(b * C_ + c) * NPIX;
    const float* cdbc = cd + (size_t)(b * C_ + c) * NPIX;

    float w0s = w_s_from_d[0];
    float wp  = w_prop[c];
    float inv_wp1 = 1.f / (wp + 1.f);
    float inv_sw  = 1.f / (sums[0] + EPSV);
    float b1 = wp * inv_wp1;
    size_t cbase = (size_t)((b * C_ + c) * 4) * NPIX;

    // fill: stage 1 on the halo-1 grid (18x34); only direction 0 survives the
    // reference's argmax over identical stacked copies.
    auto fillpx = [&](int i, auto cIN) {
        constexpr bool IN = decltype(cIN)::value;
        int y = i / TLX, x = i - y * TLX;
        int gh = h0 - 1 + y, gw = w0 - 1 + x;
        if (IN || ((unsigned)gh < (unsigned)H_ && (unsigned)gw < (unsigned)W_)) {
            float mn, cmn, mx, cmx;
            size_t q0 = (size_t)(gh - 1) * W_ + (gw - 1);
            size_t q1 = (size_t)(gh + 1) * W_ + (gw + 1);
            if constexpr (IN) {
                mn = dbc[q0]; cmn = cdbc[q0];
                mx = dbc[q1]; cmx = cdbc[q1];
            } else {
                bool ok0 = (gh >= 1 && gw >= 1);
                bool ok1 = (gh < H_ - 1 && gw < W_ - 1);
                mn  = ok0 ? dbc[q0]  : 0.f;
                cmn = ok0 ? cdbc[q0] : 0.f;
                mx  = ok1 ? dbc[q1]  : 0.f;
                cmx = ok1 ? cdbc[q1] : 0.f;
            }
            float r = __fdividef(mn, mx + EPSV);
            r = fminf(fmaxf(r, 0.f), 1.f);
            float sfd = r * fmaf(w0s, r, 1.f - w0s);
            float cfd = cmn * cmx;
            float a1 = cfd * sfd * inv_wp1;
            float c1 = cfd * inv_wp1;
            size_t gbase = cbase + (size_t)gh * W_ + gw;
            #pragma unroll
            for (int k = 0; k < 4; ++k) {
                float s_v  = s[gbase + (size_t)k * NPIX];
                float cs_v = cs[gbase + (size_t)k * NPIX];
                float t = b1 * cs_v;
                uv_[k][y][x] = make_float2(fmaf(t, s_v, a1), t + c1);
            }
        } else {
            #pragma unroll
            for (int k = 0; k < 4; ++k) uv_[k][y][x] = make_float2(0.f, 0.f);
        }
    };

    bool interior = (tx0 >= 1 && tx0 <= 4 && ty0 >= 1 && ty0 <= 10);
    if (interior) {
        fillpx(tid, TT{});
        fillpx(tid + 256, TT{});
        if (tid < TLY * TLX - 512) fillpx(tid + 512, TT{});
    } else {
        fillpx(tid, FT{});
        fillpx(tid + 256, FT{});
        if (tid < TLY * TLX - 512) fillpx(tid + 512, FT{});
    }
    __syncthreads();

    // conv: k-outer (weights -> SGPRs via uniform loads), p-inner.
    unsigned hwx[2] = {0, 0}, lwx[2] = {0, 0};
    unsigned hwy[2] = {0, 0}, lwy[2] = {0, 0};
    const float* swg = sw + c * 36;
    #pragma unroll
    for (int k = 0; k < 4; ++k) {
        float w9[9];
        #pragma unroll
        for (int j = 0; j < 9; ++j) w9[j] = swg[k * 9 + j];   // uniform -> s_load
        #pragma unroll
        for (int p = 0; p < 2; ++p) {
            int i = p * 256 + tid;
            int ty = i >> 5, tx = i & 31;
            float nom = 0.f, den = 0.f;
            #pragma unroll
            for (int dy = 0; dy < 3; ++dy)
                #pragma unroll
                for (int dx = 0; dx < 3; ++dx) {
                    float2 P = uv_[k][ty + dy][tx + dx];
                    float wgt = w9[dy * 3 + dx];
                    nom = fmaf(wgt, P.x, nom);
                    den = fmaf(wgt, P.y, den);
                }
            q14(nom * inv_sw, hwx[p], lwx[p], k);
            q14(den * inv_sw, hwy[p], lwy[p], k);
        }
    }

    #pragma unroll
    for (int p = 0; p < 2; ++p) {
        int i = p * 256 + tid;
        int ty = i >> 5, tx = i & 31;
        int pb = (h0 + ty) * (W_ / 32) + (w0 >> 5);
        size_t base = (size_t)(b * PB + pb) * 16384 + (size_t)c * 256 + (size_t)tx * 8;
        *(uint2*)(XP + base) = make_uint2(hwx[p], lwx[p]);
        *(uint2*)(YP + base) = make_uint2(hwy[p], lwy[p]);
    }
}

// ---------------- stage 3: i8 integer MFMA GEMM (LL term dropped) ------------
// R21-proven: 512 threads (8 waves), tile 256 o x 32 pix, 32 KB u8 panel via
// 4 global_load_lds; mfma_i32_16x16x64_i8, K=64 x 4 k-steps; accs HH (x2^14)
// and Mid (x2^7); two-phase counted vmcnt (6/12); transpose epilogue.
__global__ __launch_bounds__(512) void k_stage3(
    const u8* __restrict__ XP, const u8* __restrict__ YP,
    const u8* __restrict__ cwAh, const u8* __restrict__ cwAl,
    const float* __restrict__ sums, float* __restrict__ out)
{
    __shared__ u8 stg[36864];   // 32 KB panel; 36 KB epilogue transpose overlay

    int tid  = threadIdx.x;
    int wave = tid >> 6, lane = tid & 63;
    int l15 = lane & 15, l4 = lane >> 4;
    int pb = blockIdx.x;
    int b  = blockIdx.y;
    int o0 = wave * 32;

    size_t tb = (size_t)(b * PB + pb) * 16384;   // u8 tile base

    i32x4 aHH[2][2] = {}, aM[2][2] = {};
    i32x4 dHH[2][2] = {}, dM[2][2] = {};
    uint2 wx[2][4], wy[2][4];    // [n][g-row] raw limb words (.x = H, .y = L)
    i32x4 rAh[2][2], rAl[2][2];  // [bank][m]

#define MFMAI __builtin_amdgcn_mfma_i32_16x16x64_i8

#define LOADA(AB, KS) do {                                                        \
    _Pragma("unroll")                                                             \
    for (int m = 0; m < 2; ++m) {                                                 \
        size_t ro = (size_t)(o0 + m * 16 + l15) * C4 + (KS) * 64 + l4 * 16;       \
        rAh[AB][m] = *(const i32x4*)(cwAh + ro);                                  \
        rAl[AB][m] = *(const i32x4*)(cwAl + ro);                                  \
    } } while (0)

#define LOADB(KS) do {                                                            \
    int xo = (((KS) & 2) ? 16384 : 0) + (((KS) & 1) ? 4096 : 0)                   \
           + l4 * 1024 + l15 * 8;                                                 \
    _Pragma("unroll")                                                             \
    for (int n = 0; n < 2; ++n)                                                   \
        _Pragma("unroll")                                                         \
        for (int i = 0; i < 4; ++i) {                                             \
            wx[n][i] = *(const uint2*)(stg + xo + n * 128 + i * 256);             \
            wy[n][i] = *(const uint2*)(stg + xo + n * 128 + i * 256 + 8192);      \
        } } while (0)

#define COMPUTE(AB) do {                                                          \
    _Pragma("unroll")                                                             \
    for (int n = 0; n < 2; ++n) {                                                 \
        union { i32x4 v; unsigned u[4]; } BXh, BXl, BYh, BYl;                     \
        _Pragma("unroll")                                                         \
        for (int i = 0; i < 4; ++i) {                                             \
            BXh.u[i] = wx[n][i].x; BXl.u[i] = wx[n][i].y;                         \
            BYh.u[i] = wy[n][i].x; BYl.u[i] = wy[n][i].y;                         \
        }                                                                         \
        _Pragma("unroll")                                                         \
        for (int m = 0; m < 2; ++m) {                                             \
            aHH[m][n] = MFMAI(rAh[AB][m], BXh.v, aHH[m][n], 0, 0, 0);             \
            aM [m][n] = MFMAI(rAh[AB][m], BXl.v, aM [m][n], 0, 0, 0);             \
            aM [m][n] = MFMAI(rAl[AB][m], BXh.v, aM [m][n], 0, 0, 0);             \
            dHH[m][n] = MFMAI(rAh[AB][m], BYh.v, dHH[m][n], 0, 0, 0);             \
            dM [m][n] = MFMAI(rAh[AB][m], BYl.v, dM [m][n], 0, 0, 0);             \
            dM [m][n] = MFMAI(rAl[AB][m], BYh.v, dM [m][n], 0, 0, 0);             \
        } } } while (0)

    // prologue: 4 STAGE ops (8 KB each: Xlo, Ylo, Xhi, Yhi), then A bank0 (ks0)
    async_ld16(XP + tb +        (size_t)tid * 16, stg +         tid * 16);
    async_ld16(YP + tb +        (size_t)tid * 16, stg +  8192 + tid * 16);
    async_ld16(XP + tb + 8192 + (size_t)tid * 16, stg + 16384 + tid * 16);
    async_ld16(YP + tb + 8192 + (size_t)tid * 16, stg + 24576 + tid * 16);
    __builtin_amdgcn_sched_barrier(0);
    LOADA(0, 0);
    __builtin_amdgcn_sched_barrier(0);

    // Xlo+Ylo retired (8 issued, <=6 outstanding -> oldest 2 done)
    asm volatile("s_waitcnt vmcnt(6)" ::: "memory");
    __builtin_amdgcn_s_barrier();
    __builtin_amdgcn_sched_barrier(0);

    LOADA(1, 1); LOADB(0); COMPUTE(0);
    LOADA(0, 2); LOADB(1); COMPUTE(1);

    // 16 issued; all 4 STAGE retired (<=12 outstanding -> oldest 4 done)
    asm volatile("s_waitcnt vmcnt(12)" ::: "memory");
    __builtin_amdgcn_s_barrier();
    __builtin_amdgcn_sched_barrier(0);

    LOADA(1, 3); LOADB(2); COMPUTE(0);
    LOADB(3); COMPUTE(1);

#undef COMPUTE
#undef LOADB
#undef LOADA
#undef MFMAI

    // -------- epilogue: limb fold + LDS transpose -> full-line stores --------
    float* ts = reinterpret_cast<float*>(stg);   // 256 x 36 floats = 36,864 B
    float inv_scw = 1.f / (sums[1] + EPSV);
    __syncthreads();   // all LOADB consumers of stg finished

    #pragma unroll
    for (int pass2 = 0; pass2 < 2; ++pass2) {
        #pragma unroll
        for (int m = 0; m < 2; ++m)
            #pragma unroll
            for (int n = 0; n < 2; ++n)
                #pragma unroll
                for (int r = 0; r < 4; ++r) {
                    int o = o0 + m * 16 + l4 * 4 + r;
                    float n2 = fmaf((float)aHH[m][n][r], 16384.f,
                                    (float)aM[m][n][r] * 128.f) * INVQS2;
                    float d2 = fmaf((float)dHH[m][n][r], 16384.f,
                                    (float)dM[m][n][r] * 128.f) * INVQS2;
                    float val = pass2 ? d2 * inv_scw : n2 / (d2 + EPSV);
                    ts[o * 36 + n * 16 + l15] = val;
                }
        __syncthreads();
        size_t gb = (pass2 ? NT : 0) + (size_t)b * C4 * NPIX + (size_t)pb * 32;
        int oo = tid >> 3, j = tid & 7;
        #pragma unroll
        for (int pass = 0; pass < 4; ++pass) {
            int o = pass * 64 + oo;
            f32x4 v = *(const f32x4*)&ts[o * 36 + j * 4];
            *(f32x4*)&out[gb + (size_t)o * NPIX + j * 4] = v;
        }
        if (pass2 == 0) __syncthreads();
    }
}

} // namespace

extern "C" void kernel_launch(void* const* d_in, const int* in_sizes, int n_in,
                              void* d_out, int out_size, void* d_ws, size_t ws_size,
                              hipStream_t stream) {
    const float* d    = (const float*)d_in[0];
    const float* cd   = (const float*)d_in[1];
    const float* s    = (const float*)d_in[2];
    const float* cs   = (const float*)d_in[3];
    const float* w_s  = (const float*)d_in[4];
    const float* wprp = (const float*)d_in[5];
    const float* cw   = (const float*)d_in[6];
    const float* sw   = (const float*)d_in[7];
    float* out = (float*)d_out;

    u8* XP = (u8*)d_ws;                        // 2*NT bytes
    u8* YP = XP + 2 * NT;                      // 2*NT bytes
    u8* cwAh = YP + 2 * NT;                    // 65,536 B
    u8* cwAl = cwAh + C4 * C4;                 // 65,536 B
    float* sums   = (float*)(cwAl + C4 * C4);
    float* partial = sums + 2;

    k_prep<<<C4, 256, 0, stream>>>(cw, cwAh, cwAl, partial);
    k_sums2<<<1, 256, 0, stream>>>(sw, partial, sums);
    // 6 x 12 tiles per (b,c) = 9216 blocks (XCD-swizzled inside the kernel)
    k_stage12<<<dim3(B_ * C_ * (H_ / TILEH) * (W_ / TILEW)), 256, 0, stream>>>(
        d, cd, s, cs, w_s, wprp, sw, sums, XP, YP);
    k_stage3<<<dim3(PB, B_), 512, 0, stream>>>(XP, YP, cwAh, cwAl, sums, out);
}